// Round 7
// baseline (202.852 us; speedup 1.0000x reference)
//
#include <hip/hip_runtime.h>
#include <hip/hip_bf16.h>

#define N_NODES 100000
#define N_EDGES 600000
#define DIM 128
#define CAP 40    // bucket capacity per node; deg~Poisson(6), P(any>=40)~4e-15, graph fixed
#define EPB 768   // edges per linear_fill block: 782 blocks x 768 = 600576 >= E

typedef __attribute__((ext_vector_type(8))) short short8;
typedef __attribute__((ext_vector_type(4))) float f32x4;
typedef __attribute__((ext_vector_type(4))) int i32x4;
typedef __attribute__((ext_vector_type(4))) unsigned u32x4;

static __device__ __forceinline__ short f2bf(float f) {
    return __builtin_bit_cast(short, __float2bfloat16(f));
}
static __device__ __forceinline__ unsigned pack2(float a, float b) {
    unsigned lo = (unsigned short)__builtin_bit_cast(short, __float2bfloat16(a));
    unsigned hi = (unsigned short)__builtin_bit_cast(short, __float2bfloat16(b));
    return lo | (hi << 16);
}
// bf16 pair unpack from a dword: low half / high half as f32 (2 VALU total)
static __device__ __forceinline__ float bflo(unsigned u) {
    return __builtin_bit_cast(float, u << 16);
}
static __device__ __forceinline__ float bfhi(unsigned u) {
    return __builtin_bit_cast(float, u & 0xffff0000u);
}

// ---------------------------------------------------------------------------
// 1) MERGED linear + fill. Linear no longer needs degrees (dn moved to
//    gather), so edge bucketing has no upstream dependency and its pure
//    latency/writeback cost (40 us standalone, 0.4% VALU, 15% of HBM BW)
//    hides under the MFMA work of co-resident waves.
//    Layout: per block, NT-load a 768-edge chunk into regs (pinned live so
//    the compiler can't sink the loads), run the 128-node MFMA linear,
//    then do the atomic-alloc + scatter tail. cursor zeroed by memsetAsync.
//    All memory-derived values range-checked: no OOB address possible.
__global__ __launch_bounds__(256) void linear_fill(
    const float* __restrict__ H, const float* __restrict__ W,
    const float* __restrict__ b,
    const int* __restrict__ erow, const int* __restrict__ ecol,
    int* __restrict__ cursor, int* __restrict__ bucket,
    __hip_bfloat16* __restrict__ Hl)
{
    __shared__ __hip_bfloat16 Wb[DIM][DIM + 8];   // 128 x 136 bf16 = 34816 B

    const int t = threadIdx.x;
    const int wave = t >> 6;
    const int lane = t & 63;
    const int quad = lane >> 4;
    const int l16  = lane & 15;

    const int node0 = blockIdx.x * 128 + wave * 16 + l16;  // group 0
    const int node1 = node0 + 64;                          // group 1
    const bool v0 = node0 < N_NODES;
    const bool v1 = node1 < N_NODES;

    // hoist ALL global H loads for BOTH groups (one vmcnt round, max MLP)
    f32x4 ha[4][2], hb[4][2];
    if (v0) {
        const f32x4* hp = (const f32x4*)(H + (size_t)node0 * DIM);
        #pragma unroll
        for (int ks = 0; ks < 4; ++ks) {
            ha[ks][0] = __builtin_nontemporal_load(hp + ks * 8 + quad * 2);
            ha[ks][1] = __builtin_nontemporal_load(hp + ks * 8 + quad * 2 + 1);
        }
    } else {
        #pragma unroll
        for (int ks = 0; ks < 4; ++ks)
            ha[ks][0] = ha[ks][1] = (f32x4){0.f, 0.f, 0.f, 0.f};
    }
    if (v1) {
        const f32x4* hp = (const f32x4*)(H + (size_t)node1 * DIM);
        #pragma unroll
        for (int ks = 0; ks < 4; ++ks) {
            hb[ks][0] = __builtin_nontemporal_load(hp + ks * 8 + quad * 2);
            hb[ks][1] = __builtin_nontemporal_load(hp + ks * 8 + quad * 2 + 1);
        }
    } else {
        #pragma unroll
        for (int ks = 0; ks < 4; ++ks)
            hb[ks][0] = hb[ks][1] = (f32x4){0.f, 0.f, 0.f, 0.f};
    }

    // issue this block's edge-chunk loads now (NT, coalesced); consumed in
    // the tail. asm pin keeps them materialized here (no sinking).
    int er[3], ec[3];
    {
        const int ebase = blockIdx.x * EPB + t;
        #pragma unroll
        for (int i = 0; i < 3; ++i) {
            int e = ebase + i * 256;
            bool ve = e < N_EDGES;
            er[i] = ve ? __builtin_nontemporal_load(erow + e) : -1;
            ec[i] = ve ? __builtin_nontemporal_load(ecol + e) : 0;
            asm volatile("" : "+v"(er[i]), "+v"(ec[i]));
        }
    }

    // stage W -> LDS bf16 (once per 128 nodes); W is L2-hot across blocks
    for (int i = t; i < DIM * (DIM / 4); i += 256) {
        int row = i >> 5, c4 = i & 31;
        f32x4 w4 = ((const f32x4*)W)[i];
        __hip_bfloat16* dst = &Wb[row][c4 * 4];
        dst[0] = __float2bfloat16(w4.x);
        dst[1] = __float2bfloat16(w4.y);
        dst[2] = __float2bfloat16(w4.z);
        dst[3] = __float2bfloat16(w4.w);
    }
    __syncthreads();

    f32x4 acc[8];

    // ---- group 0 ----
    #pragma unroll
    for (int mt = 0; mt < 8; ++mt) acc[mt] = (f32x4){0.f, 0.f, 0.f, 0.f};
    #pragma unroll
    for (int ks = 0; ks < 4; ++ks) {
        const int k0 = ks * 32 + quad * 8;
        short8 hfr;
        hfr[0] = f2bf(ha[ks][0].x); hfr[1] = f2bf(ha[ks][0].y);
        hfr[2] = f2bf(ha[ks][0].z); hfr[3] = f2bf(ha[ks][0].w);
        hfr[4] = f2bf(ha[ks][1].x); hfr[5] = f2bf(ha[ks][1].y);
        hfr[6] = f2bf(ha[ks][1].z); hfr[7] = f2bf(ha[ks][1].w);
        #pragma unroll
        for (int mt = 0; mt < 8; ++mt) {
            short8 wfr = *(const short8*)&Wb[mt * 16 + l16][k0];
            acc[mt] = __builtin_amdgcn_mfma_f32_16x16x32_bf16(wfr, hfr, acc[mt], 0, 0, 0);
        }
    }
    if (v0) {
        #pragma unroll
        for (int mt = 0; mt < 8; ++mt) {
            f32x4 b4 = *(const f32x4*)(b + mt * 16 + quad * 4);
            uint2 pk;
            pk.x = pack2(acc[mt][0] + b4.x, acc[mt][1] + b4.y);
            pk.y = pack2(acc[mt][2] + b4.z, acc[mt][3] + b4.w);
            *(uint2*)(Hl + (size_t)node0 * DIM + mt * 16 + quad * 4) = pk;
        }
    }

    // ---- group 1 ----
    #pragma unroll
    for (int mt = 0; mt < 8; ++mt) acc[mt] = (f32x4){0.f, 0.f, 0.f, 0.f};
    #pragma unroll
    for (int ks = 0; ks < 4; ++ks) {
        const int k0 = ks * 32 + quad * 8;
        short8 hfr;
        hfr[0] = f2bf(hb[ks][0].x); hfr[1] = f2bf(hb[ks][0].y);
        hfr[2] = f2bf(hb[ks][0].z); hfr[3] = f2bf(hb[ks][0].w);
        hfr[4] = f2bf(hb[ks][1].x); hfr[5] = f2bf(hb[ks][1].y);
        hfr[6] = f2bf(hb[ks][1].z); hfr[7] = f2bf(hb[ks][1].w);
        #pragma unroll
        for (int mt = 0; mt < 8; ++mt) {
            short8 wfr = *(const short8*)&Wb[mt * 16 + l16][k0];
            acc[mt] = __builtin_amdgcn_mfma_f32_16x16x32_bf16(wfr, hfr, acc[mt], 0, 0, 0);
        }
    }
    if (v1) {
        #pragma unroll
        for (int mt = 0; mt < 8; ++mt) {
            f32x4 b4 = *(const f32x4*)(b + mt * 16 + quad * 4);
            uint2 pk;
            pk.x = pack2(acc[mt][0] + b4.x, acc[mt][1] + b4.y);
            pk.y = pack2(acc[mt][2] + b4.z, acc[mt][3] + b4.w);
            *(uint2*)(Hl + (size_t)node1 * DIM + mt * 16 + quad * 4) = pk;
        }
    }

    // ---- fill tail: one returning atomic + scatter per edge; latency
    // overlaps co-resident waves' MFMA. pos range-checked vs CAP.
    #pragma unroll
    for (int i = 0; i < 3; ++i) {
        int r = er[i];
        if ((unsigned)r < (unsigned)N_NODES) {
            int pos = atomicAdd(&cursor[r], 1);
            if ((unsigned)pos < (unsigned)CAP)
                bucket[(size_t)r * CAP + pos] = ec[i];
        }
    }
}

// one 4-node tile: 16 lanes/node, 16-B row loads. Neighbor weight is now
// dn[src] = rsqrt(deg[src]+1) (0 for tail slots) -> same FMA count as the
// old 0/1 mask; deg loads issue alongside the row loads (independent).
static __device__ __forceinline__ void gather_one(
    int node, int d, i32x4 ia, i32x4 ib, u32x4 hs,
    const i32x4* __restrict__ bp, const u32x4* __restrict__ HlV,
    const int* __restrict__ cursor, float* __restrict__ out, int l)
{
    d = min(max(d, 0), CAP);               // defensive clamp
    float dn = rsqrtf((float)d + 1.0f);

    // self term: Hl[node] * dn  (second dn factor applied at the end)
    float acc0 = bflo(hs.x) * dn, acc1 = bfhi(hs.x) * dn;
    float acc2 = bflo(hs.y) * dn, acc3 = bfhi(hs.y) * dn;
    float acc4 = bflo(hs.z) * dn, acc5 = bfhi(hs.z) * dn;
    float acc6 = bflo(hs.w) * dn, acc7 = bfhi(hs.w) * dn;

    int j = 0;
    for (;;) {
        int ids[8] = {ia.x, ia.y, ia.z, ia.w, ib.x, ib.y, ib.z, ib.w};
        u32x4 rows[8];
        int   degs[8];
        float wgt[8];
        #pragma unroll
        for (int k = 0; k < 8; ++k) {
            unsigned idx = (unsigned)ids[k];
            idx = (idx < (unsigned)N_NODES) ? idx : 0u;   // range mask
            rows[k] = HlV[idx * 16u + (unsigned)l];
            degs[k] = cursor[idx];                        // L2-hot 400KB table
        }
        bool more = __any((j + 8) < d);    // tile-uniform continue
        if (more) {                        // prefetch next ids under the FMAs
            int q = (j + 8) >> 2;          // max q=8 -> bp[9], ints 36..39 < CAP
            ia = __builtin_nontemporal_load(bp + q);
            ib = __builtin_nontemporal_load(bp + q + 1);
        }
        #pragma unroll
        for (int k = 0; k < 8; ++k) {
            int dk = min(max(degs[k], 0), CAP);
            wgt[k] = ((j + k) < d) ? rsqrtf((float)dk + 1.0f) : 0.0f;
        }
        #pragma unroll
        for (int k = 0; k < 8; ++k) {
            acc0 = fmaf(bflo(rows[k].x), wgt[k], acc0);
            acc1 = fmaf(bfhi(rows[k].x), wgt[k], acc1);
            acc2 = fmaf(bflo(rows[k].y), wgt[k], acc2);
            acc3 = fmaf(bfhi(rows[k].y), wgt[k], acc3);
            acc4 = fmaf(bflo(rows[k].z), wgt[k], acc4);
            acc5 = fmaf(bfhi(rows[k].z), wgt[k], acc5);
            acc6 = fmaf(bflo(rows[k].w), wgt[k], acc6);
            acc7 = fmaf(bfhi(rows[k].w), wgt[k], acc7);
        }
        if (!more) break;
        j += 8;
    }

    f32x4 o0, o1;
    o0.x = fmaxf(acc0 * dn, 0.f);
    o0.y = fmaxf(acc1 * dn, 0.f);
    o0.z = fmaxf(acc2 * dn, 0.f);
    o0.w = fmaxf(acc3 * dn, 0.f);
    o1.x = fmaxf(acc4 * dn, 0.f);
    o1.y = fmaxf(acc5 * dn, 0.f);
    o1.z = fmaxf(acc6 * dn, 0.f);
    o1.w = fmaxf(acc7 * dn, 0.f);
    float* op = out + (size_t)node * DIM + l * 8;
    __builtin_nontemporal_store(o0, (f32x4*)op);
    __builtin_nontemporal_store(o1, (f32x4*)(op + 4));
}

// 2) gather: 8 nodes/wave as TWO pipelined 4-node tiles (both tiles' ids,
//    self rows, cursors issue in one burst -> tile B pays only the row RT).
//    Grid 6250 x 128 covers N=100000 exactly. NT: ids (read-once) and out
//    (write-once) bypass L2 so it holds Hl.
__global__ __launch_bounds__(128) void gather_kernel(
    const int* __restrict__ cursor, const int* __restrict__ bucket,
    const __hip_bfloat16* __restrict__ Hl, float* __restrict__ out)
{
    const int t = threadIdx.x;
    const int lane = t & 63;
    const int g = lane >> 4;           // node slot within wave (0-3)
    const int l = lane & 15;           // 16 lanes x 16B = 256-B row
    const int base = blockIdx.x * 16 + ((t >> 6) << 3);  // 8 nodes per wave
    const int nodeA = base + g;        // tile A
    const int nodeB = base + 4 + g;    // tile B  (max = 99999)

    const u32x4* __restrict__ HlV = (const u32x4*)Hl;   // 16 x u32x4 per row

    const i32x4* bpA = (const i32x4*)(bucket + (size_t)nodeA * CAP);
    const i32x4* bpB = (const i32x4*)(bucket + (size_t)nodeB * CAP);
    i32x4 iaA = __builtin_nontemporal_load(bpA);
    i32x4 ibA = __builtin_nontemporal_load(bpA + 1);
    i32x4 iaB = __builtin_nontemporal_load(bpB);
    i32x4 ibB = __builtin_nontemporal_load(bpB + 1);
    u32x4 hsA = HlV[(unsigned)nodeA * 16u + (unsigned)l];
    u32x4 hsB = HlV[(unsigned)nodeB * 16u + (unsigned)l];
    int dA = cursor[nodeA];
    int dB = cursor[nodeB];

    gather_one(nodeA, dA, iaA, ibA, hsA, bpA, HlV, cursor, out, l);
    gather_one(nodeB, dB, iaB, ibB, hsB, bpB, HlV, cursor, out, l);
}

extern "C" void kernel_launch(void* const* d_in, const int* in_sizes, int n_in,
                              void* d_out, int out_size, void* d_ws, size_t ws_size,
                              hipStream_t stream) {
    const float* H  = (const float*)d_in[0];
    const int*   ei = (const int*)d_in[1];   // [2, E] int32
    const float* W  = (const float*)d_in[2];
    const float* b  = (const float*)d_in[3];
    float* out = (float*)d_out;

    char* ws = (char*)d_ws;
    __hip_bfloat16* Hl = (__hip_bfloat16*)(ws);   // 25,600,000 B
    int* cursor = (int*)(ws + 25600000);          //    400,000 B
    int* bucket = (int*)(ws + 26000000);          // 16,000,000 B (CAP*N*4)

    const int* erow = ei;             // destinations
    const int* ecol = ei + N_EDGES;   // sources

    // cursor = 0 via DMA (graph-capture-safe)
    hipMemsetAsync(cursor, 0, N_NODES * sizeof(int), stream);
    linear_fill<<<(N_NODES + 127) / 128, 256, 0, stream>>>(H, W, b, erow, ecol,
                                                           cursor, bucket, Hl);
    gather_kernel<<<(N_NODES + 15) / 16, 128, 0, stream>>>(cursor, bucket, Hl, out);
}

// Round 8
// 184.976 us; speedup vs baseline: 1.0966x; 1.0966x over previous
//
#include <hip/hip_runtime.h>
#include <hip/hip_bf16.h>

#define N_NODES 100000
#define N_EDGES 600000
#define DIM 128
#define CAP 40     // bucket capacity per node; deg~Poisson(6), P(any>=40)~4e-15, graph fixed
#define FILL_BLOCKS 586   // 586 x 1024 edges = 600064 >= E
#define LIN_BLOCKS  782   // 782 x 128 nodes = 100096 >= N

typedef __attribute__((ext_vector_type(8))) short short8;
typedef __attribute__((ext_vector_type(4))) float f32x4;
typedef __attribute__((ext_vector_type(4))) int i32x4;
typedef __attribute__((ext_vector_type(4))) unsigned u32x4;

static __device__ __forceinline__ short f2bf(float f) {
    return __builtin_bit_cast(short, __float2bfloat16(f));
}
static __device__ __forceinline__ unsigned pack2(float a, float b) {
    unsigned lo = (unsigned short)__builtin_bit_cast(short, __float2bfloat16(a));
    unsigned hi = (unsigned short)__builtin_bit_cast(short, __float2bfloat16(b));
    return lo | (hi << 16);
}
// bf16 pair unpack from a dword: low half / high half as f32 (2 VALU total)
static __device__ __forceinline__ float bflo(unsigned u) {
    return __builtin_bit_cast(float, u << 16);
}
static __device__ __forceinline__ float bfhi(unsigned u) {
    return __builtin_bit_cast(float, u & 0xffff0000u);
}

// ---------------------------------------------------------------------------
// 1) BLOCK-SPECIALIZED linear+fill. Whole blocks are either fill-blocks
//    (thin scatter path, dispatched FIRST so their latency-bound atomics
//    are co-resident with compute from t=0) or linear-blocks (MFMA path).
//    Unlike the round-7 same-block phase merge (87us, zero overlap: phases
//    synchronized grid-wide + scatter occupancy crushed to 18%), block
//    specialization lets the scatter run at its natural wave count while
//    other blocks' MFMA hides its latency.
//    cursor zeroed by memsetAsync; cursor[r] counts degree directly.
//    All memory-derived values range-checked: no OOB address possible.
__global__ __launch_bounds__(256) void linfill_kernel(
    const float* __restrict__ H, const float* __restrict__ W,
    const float* __restrict__ b,
    const int* __restrict__ erow, const int* __restrict__ ecol,
    int* __restrict__ cursor, int* __restrict__ bucket,
    __hip_bfloat16* __restrict__ Hl)
{
    __shared__ __hip_bfloat16 Wb[DIM][DIM + 8];   // 128 x 136 bf16 = 34816 B

    const int t = threadIdx.x;

    // ---------------- fill path: 1024 edges per block ----------------
    if (blockIdx.x < FILL_BLOCKS) {
        const int ebase = blockIdx.x * 1024 + t;
        #pragma unroll
        for (int i = 0; i < 4; ++i) {
            int e = ebase + i * 256;
            if (e < N_EDGES) {
                int r = __builtin_nontemporal_load(erow + e);
                int c = __builtin_nontemporal_load(ecol + e);
                if ((unsigned)r < (unsigned)N_NODES) {
                    int pos = atomicAdd(&cursor[r], 1);
                    if ((unsigned)pos < (unsigned)CAP)
                        bucket[(size_t)r * CAP + pos] = c;
                }
            }
        }
        return;
    }

    // ---------------- linear path: 128 nodes per block ----------------
    const int lb   = blockIdx.x - FILL_BLOCKS;
    const int wave = t >> 6;
    const int lane = t & 63;
    const int quad = lane >> 4;
    const int l16  = lane & 15;

    const int node0 = lb * 128 + wave * 16 + l16;   // group 0
    const int node1 = node0 + 64;                   // group 1
    const bool v0 = node0 < N_NODES;
    const bool v1 = node1 < N_NODES;

    // hoist ALL global H loads for BOTH groups (one vmcnt round, max MLP)
    f32x4 ha[4][2], hb[4][2];
    if (v0) {
        const f32x4* hp = (const f32x4*)(H + (size_t)node0 * DIM);
        #pragma unroll
        for (int ks = 0; ks < 4; ++ks) {
            ha[ks][0] = __builtin_nontemporal_load(hp + ks * 8 + quad * 2);
            ha[ks][1] = __builtin_nontemporal_load(hp + ks * 8 + quad * 2 + 1);
        }
    } else {
        #pragma unroll
        for (int ks = 0; ks < 4; ++ks)
            ha[ks][0] = ha[ks][1] = (f32x4){0.f, 0.f, 0.f, 0.f};
    }
    if (v1) {
        const f32x4* hp = (const f32x4*)(H + (size_t)node1 * DIM);
        #pragma unroll
        for (int ks = 0; ks < 4; ++ks) {
            hb[ks][0] = __builtin_nontemporal_load(hp + ks * 8 + quad * 2);
            hb[ks][1] = __builtin_nontemporal_load(hp + ks * 8 + quad * 2 + 1);
        }
    } else {
        #pragma unroll
        for (int ks = 0; ks < 4; ++ks)
            hb[ks][0] = hb[ks][1] = (f32x4){0.f, 0.f, 0.f, 0.f};
    }

    // stage W -> LDS bf16 (once per 128 nodes); W is L2-hot across blocks
    for (int i = t; i < DIM * (DIM / 4); i += 256) {
        int row = i >> 5, c4 = i & 31;
        f32x4 w4 = ((const f32x4*)W)[i];
        __hip_bfloat16* dst = &Wb[row][c4 * 4];
        dst[0] = __float2bfloat16(w4.x);
        dst[1] = __float2bfloat16(w4.y);
        dst[2] = __float2bfloat16(w4.z);
        dst[3] = __float2bfloat16(w4.w);
    }
    __syncthreads();

    f32x4 acc[8];

    // ---- group 0 ----
    #pragma unroll
    for (int mt = 0; mt < 8; ++mt) acc[mt] = (f32x4){0.f, 0.f, 0.f, 0.f};
    #pragma unroll
    for (int ks = 0; ks < 4; ++ks) {
        const int k0 = ks * 32 + quad * 8;
        short8 hfr;
        hfr[0] = f2bf(ha[ks][0].x); hfr[1] = f2bf(ha[ks][0].y);
        hfr[2] = f2bf(ha[ks][0].z); hfr[3] = f2bf(ha[ks][0].w);
        hfr[4] = f2bf(ha[ks][1].x); hfr[5] = f2bf(ha[ks][1].y);
        hfr[6] = f2bf(ha[ks][1].z); hfr[7] = f2bf(ha[ks][1].w);
        #pragma unroll
        for (int mt = 0; mt < 8; ++mt) {
            short8 wfr = *(const short8*)&Wb[mt * 16 + l16][k0];
            acc[mt] = __builtin_amdgcn_mfma_f32_16x16x32_bf16(wfr, hfr, acc[mt], 0, 0, 0);
        }
    }
    if (v0) {
        #pragma unroll
        for (int mt = 0; mt < 8; ++mt) {
            f32x4 b4 = *(const f32x4*)(b + mt * 16 + quad * 4);
            uint2 pk;
            pk.x = pack2(acc[mt][0] + b4.x, acc[mt][1] + b4.y);
            pk.y = pack2(acc[mt][2] + b4.z, acc[mt][3] + b4.w);
            *(uint2*)(Hl + (size_t)node0 * DIM + mt * 16 + quad * 4) = pk;
        }
    }

    // ---- group 1 ----
    #pragma unroll
    for (int mt = 0; mt < 8; ++mt) acc[mt] = (f32x4){0.f, 0.f, 0.f, 0.f};
    #pragma unroll
    for (int ks = 0; ks < 4; ++ks) {
        const int k0 = ks * 32 + quad * 8;
        short8 hfr;
        hfr[0] = f2bf(hb[ks][0].x); hfr[1] = f2bf(hb[ks][0].y);
        hfr[2] = f2bf(hb[ks][0].z); hfr[3] = f2bf(hb[ks][0].w);
        hfr[4] = f2bf(hb[ks][1].x); hfr[5] = f2bf(hb[ks][1].y);
        hfr[6] = f2bf(hb[ks][1].z); hfr[7] = f2bf(hb[ks][1].w);
        #pragma unroll
        for (int mt = 0; mt < 8; ++mt) {
            short8 wfr = *(const short8*)&Wb[mt * 16 + l16][k0];
            acc[mt] = __builtin_amdgcn_mfma_f32_16x16x32_bf16(wfr, hfr, acc[mt], 0, 0, 0);
        }
    }
    if (v1) {
        #pragma unroll
        for (int mt = 0; mt < 8; ++mt) {
            f32x4 b4 = *(const f32x4*)(b + mt * 16 + quad * 4);
            uint2 pk;
            pk.x = pack2(acc[mt][0] + b4.x, acc[mt][1] + b4.y);
            pk.y = pack2(acc[mt][2] + b4.z, acc[mt][3] + b4.w);
            *(uint2*)(Hl + (size_t)node1 * DIM + mt * 16 + quad * 4) = pk;
        }
    }
}

// one 4-node tile: 16 lanes/node, 16-B row loads. Neighbor weight is
// dn[src] = rsqrt(deg[src]+1) (0 for tail slots) -> same FMA count as a
// 0/1 mask; deg loads issue alongside the row loads (independent).
static __device__ __forceinline__ void gather_one(
    int node, int d, i32x4 ia, i32x4 ib, u32x4 hs,
    const i32x4* __restrict__ bp, const u32x4* __restrict__ HlV,
    const int* __restrict__ cursor, float* __restrict__ out, int l)
{
    d = min(max(d, 0), CAP);               // defensive clamp
    float dn = rsqrtf((float)d + 1.0f);

    // self term: Hl[node] * dn  (second dn factor applied at the end)
    float acc0 = bflo(hs.x) * dn, acc1 = bfhi(hs.x) * dn;
    float acc2 = bflo(hs.y) * dn, acc3 = bfhi(hs.y) * dn;
    float acc4 = bflo(hs.z) * dn, acc5 = bfhi(hs.z) * dn;
    float acc6 = bflo(hs.w) * dn, acc7 = bfhi(hs.w) * dn;

    int j = 0;
    for (;;) {
        int ids[8] = {ia.x, ia.y, ia.z, ia.w, ib.x, ib.y, ib.z, ib.w};
        u32x4 rows[8];
        int   degs[8];
        float wgt[8];
        #pragma unroll
        for (int k = 0; k < 8; ++k) {
            unsigned idx = (unsigned)ids[k];
            idx = (idx < (unsigned)N_NODES) ? idx : 0u;   // range mask
            rows[k] = HlV[idx * 16u + (unsigned)l];
            degs[k] = cursor[idx];                        // L2-hot 400KB table
        }
        bool more = __any((j + 8) < d);    // tile-uniform continue
        if (more) {                        // prefetch next ids under the FMAs
            int q = (j + 8) >> 2;          // max q=8 -> bp[9], ints 36..39 < CAP
            ia = __builtin_nontemporal_load(bp + q);
            ib = __builtin_nontemporal_load(bp + q + 1);
        }
        #pragma unroll
        for (int k = 0; k < 8; ++k) {
            int dk = min(max(degs[k], 0), CAP);
            wgt[k] = ((j + k) < d) ? rsqrtf((float)dk + 1.0f) : 0.0f;
        }
        #pragma unroll
        for (int k = 0; k < 8; ++k) {
            acc0 = fmaf(bflo(rows[k].x), wgt[k], acc0);
            acc1 = fmaf(bfhi(rows[k].x), wgt[k], acc1);
            acc2 = fmaf(bflo(rows[k].y), wgt[k], acc2);
            acc3 = fmaf(bfhi(rows[k].y), wgt[k], acc3);
            acc4 = fmaf(bflo(rows[k].z), wgt[k], acc4);
            acc5 = fmaf(bfhi(rows[k].z), wgt[k], acc5);
            acc6 = fmaf(bflo(rows[k].w), wgt[k], acc6);
            acc7 = fmaf(bfhi(rows[k].w), wgt[k], acc7);
        }
        if (!more) break;
        j += 8;
    }

    f32x4 o0, o1;
    o0.x = fmaxf(acc0 * dn, 0.f);
    o0.y = fmaxf(acc1 * dn, 0.f);
    o0.z = fmaxf(acc2 * dn, 0.f);
    o0.w = fmaxf(acc3 * dn, 0.f);
    o1.x = fmaxf(acc4 * dn, 0.f);
    o1.y = fmaxf(acc5 * dn, 0.f);
    o1.z = fmaxf(acc6 * dn, 0.f);
    o1.w = fmaxf(acc7 * dn, 0.f);
    float* op = out + (size_t)node * DIM + l * 8;
    __builtin_nontemporal_store(o0, (f32x4*)op);
    __builtin_nontemporal_store(o1, (f32x4*)(op + 4));
}

// 2) gather: 8 nodes/wave as TWO pipelined 4-node tiles (both tiles' ids,
//    self rows, cursors issue in one burst -> tile B pays only the row RT).
//    Grid 6250 x 128 covers N=100000 exactly. NT: ids (read-once) and out
//    (write-once) bypass L2 so it holds Hl.
__global__ __launch_bounds__(128) void gather_kernel(
    const int* __restrict__ cursor, const int* __restrict__ bucket,
    const __hip_bfloat16* __restrict__ Hl, float* __restrict__ out)
{
    const int t = threadIdx.x;
    const int lane = t & 63;
    const int g = lane >> 4;           // node slot within wave (0-3)
    const int l = lane & 15;           // 16 lanes x 16B = 256-B row
    const int base = blockIdx.x * 16 + ((t >> 6) << 3);  // 8 nodes per wave
    const int nodeA = base + g;        // tile A
    const int nodeB = base + 4 + g;    // tile B  (max = 99999)

    const u32x4* __restrict__ HlV = (const u32x4*)Hl;   // 16 x u32x4 per row

    const i32x4* bpA = (const i32x4*)(bucket + (size_t)nodeA * CAP);
    const i32x4* bpB = (const i32x4*)(bucket + (size_t)nodeB * CAP);
    i32x4 iaA = __builtin_nontemporal_load(bpA);
    i32x4 ibA = __builtin_nontemporal_load(bpA + 1);
    i32x4 iaB = __builtin_nontemporal_load(bpB);
    i32x4 ibB = __builtin_nontemporal_load(bpB + 1);
    u32x4 hsA = HlV[(unsigned)nodeA * 16u + (unsigned)l];
    u32x4 hsB = HlV[(unsigned)nodeB * 16u + (unsigned)l];
    int dA = cursor[nodeA];
    int dB = cursor[nodeB];

    gather_one(nodeA, dA, iaA, ibA, hsA, bpA, HlV, cursor, out, l);
    gather_one(nodeB, dB, iaB, ibB, hsB, bpB, HlV, cursor, out, l);
}

extern "C" void kernel_launch(void* const* d_in, const int* in_sizes, int n_in,
                              void* d_out, int out_size, void* d_ws, size_t ws_size,
                              hipStream_t stream) {
    const float* H  = (const float*)d_in[0];
    const int*   ei = (const int*)d_in[1];   // [2, E] int32
    const float* W  = (const float*)d_in[2];
    const float* b  = (const float*)d_in[3];
    float* out = (float*)d_out;

    char* ws = (char*)d_ws;
    __hip_bfloat16* Hl = (__hip_bfloat16*)(ws);   // 25,600,000 B
    int* cursor = (int*)(ws + 25600000);          //    400,000 B
    int* bucket = (int*)(ws + 26000000);          // 16,000,000 B (CAP*N*4)

    const int* erow = ei;             // destinations
    const int* ecol = ei + N_EDGES;   // sources

    // cursor = 0 via DMA (graph-capture-safe)
    hipMemsetAsync(cursor, 0, N_NODES * sizeof(int), stream);
    linfill_kernel<<<FILL_BLOCKS + LIN_BLOCKS, 256, 0, stream>>>(
        H, W, b, erow, ecol, cursor, bucket, Hl);
    gather_kernel<<<(N_NODES + 15) / 16, 128, 0, stream>>>(cursor, bucket, Hl, out);
}